// Round 2
// 246.165 us; speedup vs baseline: 1.0359x; 1.0359x over previous
//
#include <hip/hip_runtime.h>
#include <hip/hip_bf16.h>

#define B_  2
#define S_  2048
#define D_  1024
#define H_  16
#define HD_ 64
#define M_  (B_*S_)   // 4096

using bf16x8 = __attribute__((ext_vector_type(8))) short;
using f32x4  = __attribute__((ext_vector_type(4))) float;
using f32x16 = __attribute__((ext_vector_type(16))) float;
using u32x4  = __attribute__((ext_vector_type(4))) unsigned int;

static __device__ __forceinline__ ushort f2bf(float f) {
    __hip_bfloat16 h = __float2bfloat16(f);
    return *reinterpret_cast<ushort*>(&h);
}

// async global->LDS, 16B per lane; LDS dest = wave-uniform base + lane*16
#define GLDS16(gp, lp) __builtin_amdgcn_global_load_lds( \
    (const __attribute__((address_space(1))) void*)(gp), \
    (__attribute__((address_space(3))) void*)(lp), 16, 0, 0)

// ---------------- convert fp32 -> bf16 (same layout) ----------------
__global__ void convert_f32_bf16(const float* __restrict__ src, ushort* __restrict__ dst, int n) {
    int i = (blockIdx.x * blockDim.x + threadIdx.x) * 4;
    if (i < n) {
        float4 v = *reinterpret_cast<const float4*>(src + i);
        ushort4 o;
        o.x = f2bf(v.x); o.y = f2bf(v.y); o.z = f2bf(v.z); o.w = f2bf(v.w);
        *reinterpret_cast<ushort4*>(dst + i) = o;
    }
}

// ------------- transpose fp32 [R][C] -> bf16 [C][R] -----------------
__global__ void transpose_f32_to_bf16(const float* __restrict__ src, ushort* __restrict__ dst,
                                      int R, int C) {
    __shared__ float t[32][33];
    int c0 = blockIdx.x * 32, r0 = blockIdx.y * 32;
    int tx = threadIdx.x, ty = threadIdx.y;
    #pragma unroll
    for (int i = 0; i < 4; i++)
        t[ty + i*8][tx] = src[(size_t)(r0 + ty + i*8) * C + c0 + tx];
    __syncthreads();
    #pragma unroll
    for (int i = 0; i < 4; i++)
        dst[(size_t)(c0 + ty + i*8) * R + r0 + tx] = f2bf(t[tx][ty + i*8]);
}

// ------------- transpose bf16 V [bh][s][hd] -> [bh][hd][s] ----------
__global__ void transpose_v(const ushort* __restrict__ src, ushort* __restrict__ dst) {
    __shared__ ushort t[64][72];   // row stride 144B (16B-divisible)
    int bh = blockIdx.y, s0 = blockIdx.x * 64;
    #pragma unroll
    for (int p = 0; p < 2; p++) {
        int idx = threadIdx.x + p * 256;        // 0..511
        int r = idx >> 3, cu = (idx & 7) * 8;   // r = s-row 0..63, cu = hd 0..56
        uint4 v = *reinterpret_cast<const uint4*>(src + (size_t)bh * 131072 + (size_t)(s0 + r) * 64 + cu);
        ushort tmp[8];
        *reinterpret_cast<uint4*>(tmp) = v;
        #pragma unroll
        for (int j = 0; j < 8; j++) t[cu + j][r] = tmp[j];
    }
    __syncthreads();
    #pragma unroll
    for (int p = 0; p < 2; p++) {
        int idx = threadIdx.x + p * 256;
        int r = idx >> 3, cu = (idx & 7) * 8;   // r = hd 0..63, cu = s 0..56
        *reinterpret_cast<uint4*>(dst + (size_t)bh * 131072 + (size_t)r * S_ + s0 + cu) =
            *reinterpret_cast<uint4*>(&t[r][cu]);
    }
}

// ---------------- GEMM: C = A(bf16 [M][K]) * Bt(bf16 [N][K])^T ----------------
// m97-style: unpadded LDS tiles + global_load_lds width-16 staging.
// MODE 0: QKV epilogue (scatter, Q pre-scaled by 0.125*log2e, +bias)
// MODE 1: fp32 out [M][N] + bias
template<int MODE>
__launch_bounds__(256, 2)
__global__ void gemm_bt(const ushort* __restrict__ A, const ushort* __restrict__ Bt,
                        int Mdim, int Ndim, int Kdim,
                        ushort* __restrict__ qout, ushort* __restrict__ kout, ushort* __restrict__ vout,
                        const float* __restrict__ bq, const float* __restrict__ bk, const float* __restrict__ bv,
                        float* __restrict__ out, const float* __restrict__ bias)
{
    __shared__ __align__(16) ushort As[128][32];   // unpadded: global_load_lds order
    __shared__ __align__(16) ushort Bs[128][32];
    const int tid  = threadIdx.x;
    const int lane = tid & 63, wave = tid >> 6;
    const int wm = wave & 1, wn = wave >> 1;       // 2x2 waves -> 64x64 each
    const int m0 = blockIdx.y * 128, n0 = blockIdx.x * 128;
    const int g = lane >> 4, c = lane & 15;

    f32x4 acc[4][4];
    #pragma unroll
    for (int i = 0; i < 4; i++)
        #pragma unroll
        for (int j = 0; j < 4; j++) acc[i][j] = (f32x4){0.f, 0.f, 0.f, 0.f};

    const int lrow = lane >> 2;       // 0..15 within 16-row chunk
    const int lcol = (lane & 3) * 8;  // ushort col 0,8,16,24

    for (int kt = 0; kt < Kdim; kt += 32) {
        // 8 chunks of 16 rows each for A and B; wave w stages chunks {w, w+4}
        #pragma unroll
        for (int p = 0; p < 2; p++) {
            int ch = wave + p * 4;
            GLDS16(A  + (size_t)(m0 + ch*16 + lrow) * Kdim + kt + lcol, &As[ch*16][0]);
            GLDS16(Bt + (size_t)(n0 + ch*16 + lrow) * Kdim + kt + lcol, &Bs[ch*16][0]);
        }
        __syncthreads();
        bf16x8 af[4], bfr[4];
        #pragma unroll
        for (int t = 0; t < 4; t++) {
            af[t]  = *reinterpret_cast<const bf16x8*>(&As[wm*64 + t*16 + c][g*8]);
            bfr[t] = *reinterpret_cast<const bf16x8*>(&Bs[wn*64 + t*16 + c][g*8]);
        }
        #pragma unroll
        for (int i = 0; i < 4; i++)
            #pragma unroll
            for (int j = 0; j < 4; j++)
                acc[i][j] = __builtin_amdgcn_mfma_f32_16x16x32_bf16(af[i], bfr[j], acc[i][j], 0, 0, 0);
        __syncthreads();
    }

    const float qscale = 0.125f * 1.4426950408889634f;  // att_scale * log2e (exp2 softmax)
    #pragma unroll
    for (int i = 0; i < 4; i++) {
      #pragma unroll
      for (int j = 0; j < 4; j++) {
        #pragma unroll
        for (int r = 0; r < 4; r++) {
            int row = m0 + wm*64 + i*16 + g*4 + r;   // C/D: row=(lane>>4)*4+reg
            int col = n0 + wn*64 + j*16 + c;         //      col=lane&15
            float v = acc[i][j][r];
            if (MODE == 0) {
                int which = col >> 10;               // 0=q 1=k 2=v
                int cc = col & 1023;
                int b = row >> 11, s = row & 2047;
                int h = cc >> 6, hd = cc & 63;
                size_t dst = (((size_t)(b*H_ + h)) * S_ + s) * HD_ + hd;
                if (which == 0)      qout[dst] = f2bf((v + bq[cc]) * qscale);
                else if (which == 1) kout[dst] = f2bf(v + bk[cc]);
                else                 vout[dst] = f2bf(v + bv[cc]);
            } else {
                out[(size_t)row * Ndim + col] = v + bias[col];
            }
        }
      }
    }
}

// ---------------- flash attention, 32x32 swapped-operand in-register softmax ----------------
// S^T = K.Q^T via mfma_32x32x16 (C/D col = q) -> softmax state lane-local.
// P packed to bf16 B-frag in registers: bit-pack + __shfl_xor(32) half-wave exchange
// (semantics-guaranteed; replaces the unverified permlane/cvt_pk asm).
// O^T = Vt.P (C/D col = q again) -> alpha rescale & 1/l lane-local, zero shuffles.
// K/Vt staged via global_load_lds with XOR-swizzled per-lane global source (T2/rule21),
// double-buffered 2-phase pipeline, one barrier per 64-key tile (T3-minimum).
__launch_bounds__(256, 2)
__global__ void attn_kernel(const ushort* __restrict__ Q, const ushort* __restrict__ K,
                            const ushort* __restrict__ Vt, ushort* __restrict__ O)
{
    __shared__ __align__(16) ushort Ks[2][64][64];   // [buf][key][hd], 16B-slot XOR swizzle
    __shared__ __align__(16) ushort Vs[2][64][64];   // [buf][hd][key], same swizzle
    const int tid = threadIdx.x, lane = tid & 63, w = tid >> 6;
    const int q31 = lane & 31, hi = lane >> 5, x7 = lane & 7;

    // T1: group 4 consecutive bh per XCD so K/V (4*512KB=2MB) stay L2-resident
    int lin = blockIdx.x + gridDim.x * blockIdx.y;   // 0..511
    int xcd = lin & 7, idx = lin >> 3;
    int bh = xcd * 4 + (idx & 3);
    int qb = idx >> 2;                                // 0..15
    const int q0 = qb * 128;
    const size_t kbase = (size_t)bh * S_ * HD_;   // Q,K: [bh][s][hd]
    const size_t vbase = (size_t)bh * HD_ * S_;   // Vt:  [bh][hd][s]

    // Q B-fragments (pre-scaled by 0.125*log2e): B[col=q31][k = hi*8+j], 4 hd-chunks
    bf16x8 qf[4];
    #pragma unroll
    for (int c4 = 0; c4 < 4; c4++)
        qf[c4] = *reinterpret_cast<const bf16x8*>(
            Q + kbase + (size_t)(q0 + w*32 + q31) * HD_ + c4*16 + hi*8);

    f32x16 acc0, acc1;          // O^T: row = hd', col = q31 (acc0: hd 0-31, acc1: 32-63)
    #pragma unroll
    for (int r = 0; r < 16; r++) { acc0[r] = 0.f; acc1[r] = 0.f; }
    float m_i = -INFINITY, l_i = 0.f;

    // staging geometry: per wave 8 rows x 128B per GLDS16; swizzle folded into global src
    const int srow  = lane >> 3;              // 0..7 within chunk
    const int sslot = (lane & 7) ^ srow;      // inverse-swizzled 16B slot
    const ushort* kg = K  + kbase + (size_t)srow * HD_ + sslot * 8;
    const ushort* vg = Vt + vbase + (size_t)srow * S_  + sslot * 8;

    auto stage = [&](int buf, int kt) {
        #pragma unroll
        for (int p = 0; p < 2; p++) {
            int ch = w + p * 4;               // 8 chunks of 8 rows
            GLDS16(kg + (size_t)(kt + ch*8) * HD_, &Ks[buf][ch*8][0]);
            GLDS16(vg + (size_t)(ch*8) * S_ + kt,  &Vs[buf][ch*8][0]);
        }
    };

    auto tile = [&](const ushort (*ks)[64], const ushort (*vs)[64], int kti) {
        // ---- S^T = K.Q^T : A[row=key=q31][k=hd], out col = q31 ----
        f32x16 st;
        #pragma unroll
        for (int r = 0; r < 16; r++) st[r] = 0.f;
        __builtin_amdgcn_s_setprio(1);
        #pragma unroll
        for (int c4 = 0; c4 < 4; c4++) {
            bf16x8 kf = *reinterpret_cast<const bf16x8*>(
                &ks[kti*32 + q31][(((c4*2 + hi) ^ x7)) * 8]);
            st = __builtin_amdgcn_mfma_f32_32x32x16_bf16(kf, qf[c4], st, 0, 0, 0);
        }
        __builtin_amdgcn_s_setprio(0);

        // ---- online softmax, lane-local (q = q31); T13 defer-max THR=8 (exp2 dom) ----
        float pm = st[0];
        #pragma unroll
        for (int r = 1; r < 16; r++) pm = fmaxf(pm, st[r]);
        pm = fmaxf(pm, __shfl_xor(pm, 32));
        if (__any(pm > m_i + 8.f)) {
            float mnew = fmaxf(m_i, pm);
            float al = exp2f(m_i - mnew);
            l_i *= al;
            #pragma unroll
            for (int r = 0; r < 16; r++) { acc0[r] *= al; acc1[r] *= al; }
            m_i = mnew;
        }
        // P pairs -> packed bf16 words; st reg r -> key (r&3)+8*(r>>2)+4*hi
        float rs = 0.f;
        unsigned int dd[8];
        #pragma unroll
        for (int r2 = 0; r2 < 8; r2++) {
            float p0 = exp2f(st[r2*2]     - m_i);
            float p1 = exp2f(st[r2*2 + 1] - m_i);
            rs += p0 + p1;
            dd[r2] = (unsigned int)f2bf(p0) | ((unsigned int)f2bf(p1) << 16);
        }
        rs += __shfl_xor(rs, 32);
        l_i += rs;
        // half-wave exchange: partner (lane^32) holds the complementary key pairs
        unsigned int ee[8];
        #pragma unroll
        for (int r2 = 0; r2 < 8; r2++)
            ee[r2] = (unsigned int)__shfl_xor((int)dd[r2], 32);
        // B-frag word w holds keys hi*8 + {2w, 2w+1} (pf0: keys 0-15; pf1: keys 16-31)
        u32x4 t0 = { hi ? ee[2] : dd[0], hi ? ee[3] : dd[1],
                     hi ? dd[2] : ee[0], hi ? dd[3] : ee[1] };
        u32x4 t1 = { hi ? ee[6] : dd[4], hi ? ee[7] : dd[5],
                     hi ? dd[6] : ee[4], hi ? dd[7] : ee[5] };
        bf16x8 pf0 = *reinterpret_cast<bf16x8*>(&t0);
        bf16x8 pf1 = *reinterpret_cast<bf16x8*>(&t1);

        // ---- O^T += Vt.P : A[row=hd'=q31][k=key], B = P ----
        bf16x8 vf00 = *reinterpret_cast<const bf16x8*>(&vs[q31]     [((kti*4 + 0 + hi) ^ x7) * 8]);
        bf16x8 vf01 = *reinterpret_cast<const bf16x8*>(&vs[q31]     [((kti*4 + 2 + hi) ^ x7) * 8]);
        bf16x8 vf10 = *reinterpret_cast<const bf16x8*>(&vs[32 + q31][((kti*4 + 0 + hi) ^ x7) * 8]);
        bf16x8 vf11 = *reinterpret_cast<const bf16x8*>(&vs[32 + q31][((kti*4 + 2 + hi) ^ x7) * 8]);
        __builtin_amdgcn_s_setprio(1);
        acc0 = __builtin_amdgcn_mfma_f32_32x32x16_bf16(vf00, pf0, acc0, 0, 0, 0);
        acc0 = __builtin_amdgcn_mfma_f32_32x32x16_bf16(vf01, pf1, acc0, 0, 0, 0);
        acc1 = __builtin_amdgcn_mfma_f32_32x32x16_bf16(vf10, pf0, acc1, 0, 0, 0);
        acc1 = __builtin_amdgcn_mfma_f32_32x32x16_bf16(vf11, pf1, acc1, 0, 0, 0);
        __builtin_amdgcn_s_setprio(0);
    };

    // ---- 2-phase pipelined main loop: stage(next) || compute(cur), 1 barrier/iter ----
    stage(0, 0);
    __syncthreads();
    #pragma unroll 1
    for (int it = 0; it < 31; ++it) {
        stage((it & 1) ^ 1, (it + 1) * 64);
        tile(Ks[it & 1], Vs[it & 1], 0);
        tile(Ks[it & 1], Vs[it & 1], 1);
        __syncthreads();                 // drains vmcnt (next tile arrived) + protects reuse
    }
    tile(Ks[1], Vs[1], 0);               // it=31 (odd -> buf 1), no prefetch
    tile(Ks[1], Vs[1], 1);

    // ---- epilogue: lane-local 1/l; O[s = q0+w*32+q31][hd = rg*8 + hi*4 + j (+32)] ----
    float inv = 1.f / l_i;
    const int b = bh >> 4, h = bh & 15;
    const int s = q0 + w*32 + q31;
    ushort* op = O + (size_t)(b*S_ + s) * 1024 + h*64;
    #pragma unroll
    for (int rg = 0; rg < 4; rg++) {
        int hd0 = rg*8 + hi*4;
        ushort4 o;
        o.x = f2bf(acc0[rg*4+0] * inv);
        o.y = f2bf(acc0[rg*4+1] * inv);
        o.z = f2bf(acc0[rg*4+2] * inv);
        o.w = f2bf(acc0[rg*4+3] * inv);
        *reinterpret_cast<ushort4*>(op + hd0) = o;
        o.x = f2bf(acc1[rg*4+0] * inv);
        o.y = f2bf(acc1[rg*4+1] * inv);
        o.z = f2bf(acc1[rg*4+2] * inv);
        o.w = f2bf(acc1[rg*4+3] * inv);
        *reinterpret_cast<ushort4*>(op + 32 + hd0) = o;
    }
}

extern "C" void kernel_launch(void* const* d_in, const int* in_sizes, int n_in,
                              void* d_out, int out_size, void* d_ws, size_t ws_size,
                              hipStream_t stream)
{
    const float* x  = (const float*)d_in[0];
    const float* wq = (const float*)d_in[1];
    const float* bq = (const float*)d_in[2];
    const float* wk = (const float*)d_in[3];
    const float* bk = (const float*)d_in[4];
    const float* wv = (const float*)d_in[5];
    const float* bv = (const float*)d_in[6];
    const float* wo = (const float*)d_in[7];
    const float* bo = (const float*)d_in[8];
    float* out = (float*)d_out;

    char* ws = (char*)d_ws;
    ushort* xb    = (ushort*)(ws);                      // 8 MB  x bf16; reused as vtw after gemm1
    ushort* wqkvT = (ushort*)(ws + (8ull  << 20));      // 6 MB  [3072][1024]
    ushort* woT   = (ushort*)(ws + (14ull << 20));      // 2 MB
    ushort* qw    = (ushort*)(ws + (16ull << 20));      // 8 MB  [bh][s][hd]
    ushort* kw    = (ushort*)(ws + (24ull << 20));      // 8 MB
    ushort* vw    = (ushort*)(ws + (32ull << 20));      // 8 MB  [bh][s][hd]
    ushort* ao    = (ushort*)(ws + (40ull << 20));      // 8 MB
    ushort* vtw   = xb;                                 // [bh][hd][s], reuses xb region

    convert_f32_bf16<<<4096, 256, 0, stream>>>(x, xb, M_ * D_);
    dim3 tb(32, 8);
    transpose_f32_to_bf16<<<dim3(32, 32), tb, 0, stream>>>(wq, wqkvT,               1024, 1024);
    transpose_f32_to_bf16<<<dim3(32, 32), tb, 0, stream>>>(wk, wqkvT + 1024*1024,   1024, 1024);
    transpose_f32_to_bf16<<<dim3(32, 32), tb, 0, stream>>>(wv, wqkvT + 2*1024*1024, 1024, 1024);
    transpose_f32_to_bf16<<<dim3(32, 32), tb, 0, stream>>>(wo, woT,                 1024, 1024);

    // QKV: M=4096, N=3072, K=1024
    gemm_bt<0><<<dim3(24, 32), 256, 0, stream>>>(xb, wqkvT, M_, 3072, 1024,
                                                 qw, kw, vw, bq, bk, bv, nullptr, nullptr);
    // V -> V^T per head (xb no longer needed)
    transpose_v<<<dim3(32, 32), 256, 0, stream>>>(vw, vtw);
    // attention
    attn_kernel<<<dim3(16, 32), 256, 0, stream>>>(qw, kw, vtw, ao);
    // out proj: M=4096, N=1024, K=1024
    gemm_bt<1><<<dim3(8, 32), 256, 0, stream>>>(ao, woT, M_, 1024, 1024,
                                                nullptr, nullptr, nullptr, nullptr, nullptr, nullptr,
                                                out, bo);
}